// Round 3
// baseline (166.804 us; speedup 1.0000x reference)
//
#include <hip/hip_runtime.h>

#define DEV static __device__ __forceinline__

// Compile-time-folded element access (j constant after full unroll).
DEV float elem(const float4& v, int j) {
  switch (j & 3) {
    case 0: return v.x;
    case 1: return v.y;
    case 2: return v.z;
    default: return v.w;
  }
}
DEV void setelem(float4& v, int j, float x) {
  switch (j & 3) {
    case 0: v.x = x; break;
    case 1: v.y = x; break;
    case 2: v.z = x; break;
    default: v.w = x; break;
  }
}

// ---------------------------------------------------------------------------
// Chunked linear-decomposition path (P == 12).
//
// State x = (level, trend, s[0..11]) evolves affinely. Split T into K chunks
// of q periods (12q steps, chunk starts on a period boundary). Pass1:
// particular solution from zero state per chunk. Combine: x_{c+1} = A x_c +
// p_c with analytic A. Pass2: exact recurrence per chunk from its true state.
//
// tid mapping is CHUNK-FASTEST (tid = n*K + c) so one wave's 64 lanes cover
// the chunks of ~one series: per-wave window = 18 KB contiguous per array
// (L1-resident) instead of 64 rows x 16 KB (1 MB, L1/L2-thrashing).
// ws layout: float4 ws[N][K][4]  (l, tr, s0..s11, pad2) = 64 B per (n,c).
// ---------------------------------------------------------------------------

__global__ __launch_bounds__(256) void ets_pass1(
    const float* __restrict__ alpha_, const float* __restrict__ beta_,
    const float* __restrict__ gamma_, const float* __restrict__ err,
    float4* __restrict__ ws, int N, int T, int q, int K)
{
  int tid = blockIdx.x * blockDim.x + threadIdx.x;
  if (tid >= N * K) return;
  int n = tid / K, c = tid - n * K;

  float a = alpha_[n], b = beta_[n], g = gamma_[n];
  float ab = a * b, ig = 1.0f - g;
  float l = 0.0f, tr = 0.0f;
  float s[12];
#pragma unroll
  for (int j = 0; j < 12; ++j) s[j] = 0.0f;

  int nper = T / 12;
  int p0 = c * q;
  int nk = min(q, nper - p0);
  const float* er = err + (size_t)n * T + (size_t)p0 * 12;

  float4 A0, A1, A2, B0, B1, B2;
  auto loadp = [&](int k, float4& e0, float4& e1, float4& e2) {
    const float4* e4 = reinterpret_cast<const float4*>(er + k * 12);
    e0 = e4[0]; e1 = e4[1]; e2 = e4[2];
  };
  auto comp = [&](const float4& e0, const float4& e1, const float4& e2) {
#pragma unroll
    for (int j = 0; j < 12; ++j) {
      float ej = elem(j < 4 ? e0 : (j < 8 ? e1 : e2), j);
      float se = s[j] + ej;
      float lt = l + tr;
      l  = fmaf(a, se, lt);
      tr = fmaf(ab, se, tr);
      s[j] = fmaf(g, ej, ig * s[j]);
    }
  };

  int k = 0;
  if (nk > 0) loadp(0, A0, A1, A2);
  for (; k + 2 <= nk; k += 2) {
    loadp(k + 1, B0, B1, B2);
    comp(A0, A1, A2);
    if (k + 2 < nk) loadp(k + 2, A0, A1, A2);
    comp(B0, B1, B2);
  }
  if (k < nk) comp(A0, A1, A2);

  if (c == K - 1) {  // tail (< 12 steps), slot phase starts at 0
    int tail = T - nper * 12;
    if (tail > 0) {
      const float* et = err + (size_t)n * T + (size_t)nper * 12;
#pragma unroll
      for (int j = 0; j < 11; ++j) {
        if (j < tail) {
          float ej = et[j];
          float se = s[j] + ej;
          float lt = l + tr;
          l  = fmaf(a, se, lt);
          tr = fmaf(ab, se, tr);
          s[j] = fmaf(g, ej, ig * s[j]);
        }
      }
    }
  }

  float4* w = ws + ((size_t)n * K + c) * 4;
  w[0] = make_float4(l, tr, s[0], s[1]);
  w[1] = make_float4(s[2], s[3], s[4], s[5]);
  w[2] = make_float4(s[6], s[7], s[8], s[9]);
  w[3] = make_float4(s[10], s[11], 0.0f, 0.0f);
}

// One thread per series; sequential over K chunks with batch-8 prefetch.
// In-place: reads particular state p_c, overwrites slot with true initial x_c.
__global__ __launch_bounds__(256) void ets_combine(
    const float* __restrict__ alpha_, const float* __restrict__ beta_,
    const float* __restrict__ gamma_, const float* __restrict__ lvl0,
    const float* __restrict__ tr0, const float* __restrict__ seas0,
    float4* __restrict__ ws, int N, int q, int K)
{
  int n = blockIdx.x * blockDim.x + threadIdx.x;
  if (n >= N) return;
  float a = alpha_[n], b = beta_[n], g = gamma_[n];
  float ab = a * b, d = 1.0f - g;

  // Homogeneous map over one chunk of q periods (L = 12q steps):
  //   s_j -> d^q s_j
  //   l  -> l + L*tr + sum_j C_j s_j,   C_j = a*S0 + ab*((L-1-j)*S0 - 12*S1)
  //   tr -> tr + ab*S0 * sum_j s_j
  // with S0 = sum_{k<q} d^k, S1 = sum_{k<q} k d^k.
  float S0 = 0.0f, S1 = 0.0f, dk = 1.0f;
  for (int kk = 0; kk < q; ++kk) { S0 += dk; S1 += (float)kk * dk; dk *= d; }
  float decay = dk;
  float F = ab * S0;
  float Lf = 12.0f * (float)q;
  float C[12];
#pragma unroll
  for (int j = 0; j < 12; ++j)
    C[j] = fmaf(a, S0, ab * ((Lf - 1.0f - (float)j) * S0 - 12.0f * S1));

  float l = lvl0[n], tr = tr0[n];
  float s[12];
#pragma unroll
  for (int j = 0; j < 12; ++j) s[j] = seas0[(size_t)n * 12 + j];

  float4* wsn = ws + (size_t)n * K * 4;

  for (int cb = 0; cb < K; cb += 8) {
    float4 pb[8][4];
#pragma unroll
    for (int u = 0; u < 8; ++u) {
      int c = cb + u;
      if (c < K) {
        const float4* p = wsn + (size_t)c * 4;
        pb[u][0] = p[0]; pb[u][1] = p[1]; pb[u][2] = p[2]; pb[u][3] = p[3];
      }
    }
#pragma unroll
    for (int u = 0; u < 8; ++u) {
      int c = cb + u;
      if (c < K) {
        float4* p = wsn + (size_t)c * 4;
        p[0] = make_float4(l, tr, s[0], s[1]);
        p[1] = make_float4(s[2], s[3], s[4], s[5]);
        p[2] = make_float4(s[6], s[7], s[8], s[9]);
        p[3] = make_float4(s[10], s[11], 0.0f, 0.0f);
        if (c < K - 1) {
          float ssum = 0.0f, lc = 0.0f;
#pragma unroll
          for (int j = 0; j < 12; ++j) { ssum += s[j]; lc = fmaf(C[j], s[j], lc); }
          float nl  = l + Lf * tr + lc + pb[u][0].x;
          float ntr = fmaf(F, ssum, tr) + pb[u][0].y;
          float ps[12] = {pb[u][0].z, pb[u][0].w, pb[u][1].x, pb[u][1].y,
                          pb[u][1].z, pb[u][1].w, pb[u][2].x, pb[u][2].y,
                          pb[u][2].z, pb[u][2].w, pb[u][3].x, pb[u][3].y};
#pragma unroll
          for (int j = 0; j < 12; ++j) s[j] = fmaf(decay, s[j], ps[j]);
          l = nl; tr = ntr;
        }
      }
    }
  }
}

__global__ __launch_bounds__(256) void ets_pass2(
    const float* __restrict__ alpha_, const float* __restrict__ beta_,
    const float* __restrict__ gamma_, const float* __restrict__ obs,
    const float* __restrict__ err, const float4* __restrict__ ws,
    float* __restrict__ out, int N, int T, int q, int K)
{
  int tid = blockIdx.x * blockDim.x + threadIdx.x;
  if (tid >= N * K) return;
  int n = tid / K, c = tid - n * K;

  float a = alpha_[n], b = beta_[n], g = gamma_[n];
  float ab = a * b, ig = 1.0f - g;

  const float4* w = ws + ((size_t)n * K + c) * 4;
  float4 w0 = w[0], w1 = w[1], w2 = w[2], w3 = w[3];
  float l = w0.x, tr = w0.y;
  float s[12] = {w0.z, w0.w, w1.x, w1.y, w1.z, w1.w,
                 w2.x, w2.y, w2.z, w2.w, w3.x, w3.y};

  int nper = T / 12;
  int p0 = c * q;
  int nk = min(q, nper - p0);
  const float* er = err + (size_t)n * T + (size_t)p0 * 12;
  const float* on = obs + (size_t)n * T + (size_t)p0 * 12;
  float*       yo = out + (size_t)n * T + (size_t)p0 * 12;

  struct Per { float4 e0, e1, e2, o0, o1, o2; };
  Per A, B;
  auto loadp = [&](int k, Per& Pp) {
    const float4* e4 = reinterpret_cast<const float4*>(er + k * 12);
    const float4* o4 = reinterpret_cast<const float4*>(on + k * 12);
    Pp.e0 = e4[0]; Pp.e1 = e4[1]; Pp.e2 = e4[2];
    Pp.o0 = o4[0]; Pp.o1 = o4[1]; Pp.o2 = o4[2];
  };
  auto comp = [&](const Per& Pp, int k) {
    float4 y0, y1, y2;
#pragma unroll
    for (int j = 0; j < 12; ++j) {
      float ej = elem(j < 4 ? Pp.e0 : (j < 8 ? Pp.e1 : Pp.e2), j);
      float oj = elem(j < 4 ? Pp.o0 : (j < 8 ? Pp.o1 : Pp.o2), j);
      float lt  = l + tr;
      float cur = lt + s[j];
      float yv  = fmaf(oj, 0.1f, cur);
      float se  = s[j] + ej;
      l  = fmaf(a, se, lt);
      tr = fmaf(ab, se, tr);
      s[j] = fmaf(g, ej, ig * s[j]);
      float4& yd = (j < 4 ? y0 : (j < 8 ? y1 : y2));
      setelem(yd, j, yv);
    }
    float4* y4 = reinterpret_cast<float4*>(yo + k * 12);
    y4[0] = y0; y4[1] = y1; y4[2] = y2;
  };

  int k = 0;
  if (nk > 0) loadp(0, A);
  for (; k + 2 <= nk; k += 2) {
    loadp(k + 1, B);
    comp(A, k);
    if (k + 2 < nk) loadp(k + 2, A);
    comp(B, k + 1);
  }
  if (k < nk) comp(A, k);

  if (c == K - 1) {  // tail
    int tail = T - nper * 12;
    if (tail > 0) {
      const float* et = err + (size_t)n * T + (size_t)nper * 12;
      const float* ot = obs + (size_t)n * T + (size_t)nper * 12;
      float*       yt = out + (size_t)n * T + (size_t)nper * 12;
#pragma unroll
      for (int j = 0; j < 11; ++j) {
        if (j < tail) {
          float ej = et[j], oj = ot[j];
          float lt  = l + tr;
          float cur = lt + s[j];
          yt[j] = fmaf(oj, 0.1f, cur);
          float se = s[j] + ej;
          l  = fmaf(a, se, lt);
          tr = fmaf(ab, se, tr);
          s[j] = fmaf(g, ej, ig * s[j]);
        }
      }
    }
  }
}

// ---------------------------------------------------------------------------
// Fallback monolithic kernels (round-0, verified correct).
// ---------------------------------------------------------------------------

struct Chunk {
  float4 o0, o1, o2;
  float4 e0, e1, e2;
};

__global__ __launch_bounds__(64, 1) void ets_p12(
    const float* __restrict__ alpha_, const float* __restrict__ beta_,
    const float* __restrict__ gamma_, const float* __restrict__ lvl0,
    const float* __restrict__ tr0, const float* __restrict__ seas0,
    const float* __restrict__ obs, const float* __restrict__ err,
    float* __restrict__ out, int N, int T)
{
  int n = blockIdx.x * blockDim.x + threadIdx.x;
  if (n >= N) return;

  float a = alpha_[n], b = beta_[n], g = gamma_[n];
  float ia = 1.0f - a, ib = 1.0f - b, ig = 1.0f - g;
  float level = lvl0[n], trend = tr0[n];

  float s[12];
#pragma unroll
  for (int j = 0; j < 12; ++j) s[j] = seas0[(size_t)n * 12 + j];

  const float* on = obs + (size_t)n * T;
  const float* er = err + (size_t)n * T;
  float*       yo = out + (size_t)n * T;

  auto load = [&](Chunk& ch, int c) {
    const float4* o4 = reinterpret_cast<const float4*>(on + c * 12);
    const float4* e4 = reinterpret_cast<const float4*>(er + c * 12);
    ch.o0 = o4[0]; ch.o1 = o4[1]; ch.o2 = o4[2];
    ch.e0 = e4[0]; ch.e1 = e4[1]; ch.e2 = e4[2];
  };

  auto compute = [&](Chunk& ch, int c) {
    float4 y0, y1, y2;
#pragma unroll
    for (int j = 0; j < 12; ++j) {
      float onj = elem(j < 4 ? ch.o0 : (j < 8 ? ch.o1 : ch.o2), j);
      float ej  = elem(j < 4 ? ch.e0 : (j < 8 ? ch.e1 : ch.e2), j);
      float sj  = s[j];
      float cur = level + trend + sj;
      float yv  = fmaf(onj, 0.1f, cur);
      float lt  = level + trend;
      float nl  = fmaf(a, cur + ej, ia * lt);
      float nt  = fmaf(b, nl - level, ib * trend);
      s[j]      = fmaf(g, ej, ig * sj);
      level = nl; trend = nt;
      float4& yd = (j < 4 ? y0 : (j < 8 ? y1 : y2));
      setelem(yd, j, yv);
    }
    float4* y4 = reinterpret_cast<float4*>(yo + c * 12);
    y4[0] = y0; y4[1] = y1; y4[2] = y2;
  };

  int nch = T / 12;
  int c = 0;
  if (nch >= 3) {
    Chunk A, B, C, D;
    load(A, 0); load(B, 1); load(C, 2);
    while (c + 6 < nch) {
      load(D, c + 3); compute(A, c);
      load(A, c + 4); compute(B, c + 1);
      load(B, c + 5); compute(C, c + 2);
      load(C, c + 6); compute(D, c + 3);
      c += 4;
    }
    int r = nch - c;
    if (r > 3) load(D, c + 3);
    compute(A, c);
    if (r > 4) load(A, c + 4);
    compute(B, c + 1);
    if (r > 5) load(B, c + 5);
    compute(C, c + 2);
    if (r > 3) compute(D, c + 3);
    if (r > 4) compute(A, c + 4);
    if (r > 5) compute(B, c + 5);
    c = nch;
  }

  int t0 = c * 12;
  int rem = T - t0;
  if (rem > 0) {
#pragma unroll
    for (int j = 0; j < 11; ++j) {
      if (j < rem) {
        float onj = on[t0 + j], ej = er[t0 + j];
        float sj  = s[j];
        float cur = level + trend + sj;
        yo[t0 + j] = fmaf(onj, 0.1f, cur);
        float lt  = level + trend;
        float nl  = fmaf(a, cur + ej, ia * lt);
        float nt  = fmaf(b, nl - level, ib * trend);
        s[j]      = fmaf(g, ej, ig * sj);
        level = nl; trend = nt;
      }
    }
  }
}

__global__ void ets_gen(
    const float* __restrict__ alpha_, const float* __restrict__ beta_,
    const float* __restrict__ gamma_, const float* __restrict__ lvl0,
    const float* __restrict__ tr0, const float* __restrict__ seas0,
    const float* __restrict__ obs, const float* __restrict__ err,
    float* __restrict__ out, int N, int T, int P)
{
  extern __shared__ float smem[];
  int n = blockIdx.x * blockDim.x + threadIdx.x;
  if (n >= N) return;
  float* s = smem + (size_t)threadIdx.x * P;
  for (int j = 0; j < P; ++j) s[j] = seas0[(size_t)n * P + j];

  float a = alpha_[n], b = beta_[n], g = gamma_[n];
  float ia = 1.0f - a, ib = 1.0f - b, ig = 1.0f - g;
  float level = lvl0[n], trend = tr0[n];

  const float* on = obs + (size_t)n * T;
  const float* er = err + (size_t)n * T;
  float*       yo = out + (size_t)n * T;

  int idx = 0;
  for (int t = 0; t < T; ++t) {
    float onj = on[t], ej = er[t];
    float sj  = s[idx];
    float cur = level + trend + sj;
    yo[t] = fmaf(onj, 0.1f, cur);
    float lt  = level + trend;
    float nl  = fmaf(a, cur + ej, ia * lt);
    float nt  = fmaf(b, nl - level, ib * trend);
    s[idx]    = fmaf(g, ej, ig * sj);
    level = nl; trend = nt;
    if (++idx == P) idx = 0;
  }
}

extern "C" void kernel_launch(void* const* d_in, const int* in_sizes, int n_in,
                              void* d_out, int out_size, void* d_ws, size_t ws_size,
                              hipStream_t stream) {
  (void)n_in; (void)out_size;
  const float* alpha = (const float*)d_in[0];
  const float* beta  = (const float*)d_in[1];
  const float* gamma = (const float*)d_in[2];
  const float* lvl0  = (const float*)d_in[3];
  const float* tr0   = (const float*)d_in[4];
  const float* seas0 = (const float*)d_in[5];
  const float* obs   = (const float*)d_in[6];
  const float* err   = (const float*)d_in[7];
  float* y = (float*)d_out;

  int N = in_sizes[0];
  int P = in_sizes[5] / N;
  int T = in_sizes[6] / N;

  if (P == 12 && (T % 4) == 0 && T >= 48 && d_ws != nullptr) {
    int nper = T / 12;
    // Pick smallest q >= 6 whose state array fits the workspace.
    int q = 0, K = 0;
    for (int qq = 6; qq <= nper; ++qq) {
      int KK = (nper + qq - 1) / qq;
      if ((size_t)KK * (size_t)N * 64u <= ws_size) { q = qq; K = KK; break; }
    }
    if (K >= 2) {
      float4* w = (float4*)d_ws;
      int threads = N * K;
      dim3 blk(256);
      dim3 gpass((threads + 255) / 256);
      ets_pass1<<<gpass, blk, 0, stream>>>(alpha, beta, gamma, err, w, N, T, q, K);
      ets_combine<<<dim3((N + 255) / 256), blk, 0, stream>>>(
          alpha, beta, gamma, lvl0, tr0, seas0, w, N, q, K);
      ets_pass2<<<gpass, blk, 0, stream>>>(alpha, beta, gamma, obs, err, w, y, N, T, q, K);
      return;
    }
  }

  if (P == 12 && (T % 4) == 0 && (T / 12) >= 3) {
    dim3 block(64), grid((N + 63) / 64);
    ets_p12<<<grid, block, 0, stream>>>(alpha, beta, gamma, lvl0, tr0, seas0,
                                        obs, err, y, N, T);
  } else {
    int bs = 64;
    size_t sh = (size_t)bs * (size_t)P * sizeof(float);
    ets_gen<<<dim3((N + bs - 1) / bs), dim3(bs), sh, stream>>>(
        alpha, beta, gamma, lvl0, tr0, seas0, obs, err, y, N, T, P);
  }
}

// Round 5
// 66.711 us; speedup vs baseline: 2.5004x; 2.5004x over previous
//
#include <hip/hip_runtime.h>

#define DEV static __device__ __forceinline__

// Skewed LDS addressing: physical = j + j/32. Breaks the 72-float chunk
// stride (multiple of 32 banks) into ~2-way conflicts. Max phys for T=4096:
// 4095 + 127 = 4222 < 4224.
#define SKEW(j) ((j) + ((j) >> 5))

// ---------------------------------------------------------------------------
// Wave-per-series kernel (P == 12, T % 4 == 0, 12 <= T <= 4096).
//
// One 64-lane wave owns one series. err/obs rows staged to LDS with coalesced
// float4 loads. Lane l owns m(l) in {base, base+1} whole seasonal periods.
// The ETS state x = (level, trend, s[0..11]) evolves affinely; over whole
// periods the homogeneous map lives in the 15-param family
//   l  -> l + L*tr + sum_j c_j s_j
//   tr -> tr + f * sum_j s_j
//   s_j-> d * s_j
// which is CLOSED under composition (verified algebraically + numerically in
// rounds 1-2). Per-lane map: analytic (geometric sums of d = 1-gamma);
// particular part: pass1 recurrence from zero state. A 6-round Kogge-Stone
// shuffle scan composes the 64 per-lane affine maps; lane l then gets its
// true initial state and pass2 emits y. No global workspace, single dispatch.
// ---------------------------------------------------------------------------
__global__ __launch_bounds__(64) void ets_wave(
    const float* __restrict__ alpha_, const float* __restrict__ beta_,
    const float* __restrict__ gamma_, const float* __restrict__ lvl0,
    const float* __restrict__ tr0, const float* __restrict__ seas0,
    const float* __restrict__ obs, const float* __restrict__ err,
    float* __restrict__ out, int T)
{
  __shared__ float er_s[4224];  // err, later reused for y
  __shared__ float ob_s[4224];

  const int n = blockIdx.x;
  const int lane = threadIdx.x;

  const float4* ER4 = reinterpret_cast<const float4*>(err + (size_t)n * T);
  const float4* OB4 = reinterpret_cast<const float4*>(obs + (size_t)n * T);
  const int nf4 = T >> 2;

  // Coalesced stage-in: 1 KB per wave load instruction.
#pragma unroll 4
  for (int i = lane; i < nf4; i += 64) {
    float4 e = ER4[i];
    float4 o = OB4[i];
    int j = i << 2;
    er_s[SKEW(j + 0)] = e.x; er_s[SKEW(j + 1)] = e.y;
    er_s[SKEW(j + 2)] = e.z; er_s[SKEW(j + 3)] = e.w;
    ob_s[SKEW(j + 0)] = o.x; ob_s[SKEW(j + 1)] = o.y;
    ob_s[SKEW(j + 2)] = o.z; ob_s[SKEW(j + 3)] = o.w;
  }

  const float a = alpha_[n], b = beta_[n], g = gamma_[n];
  const float ab = a * b, ig = 1.0f - g;

  const int nper = T / 12;
  const int base = nper >> 6, rem = nper & 63;
  const int m  = base + (lane < rem ? 1 : 0);           // periods this lane owns
  const int p0 = lane * base + min(lane, rem);          // first period
  const int t0 = p0 * 12;

  __syncthreads();

  // ---- pass1: particular solution from zero state -------------------------
  float l = 0.f, tr = 0.f, s[12];
#pragma unroll
  for (int j = 0; j < 12; ++j) s[j] = 0.f;
  {
    int t = t0;
    for (int u = 0; u < m; ++u, t += 12) {
#pragma unroll
      for (int j = 0; j < 12; ++j) {
        float e = er_s[SKEW(t + j)];
        float se = s[j] + e;
        float lt = l + tr;
        l  = fmaf(a, se, lt);
        tr = fmaf(ab, se, tr);
        s[j] = fmaf(g, e, ig * s[j]);
      }
    }
  }

  // ---- analytic homogeneous map for this lane's m periods -----------------
  float S0 = 0.f, S1 = 0.f, dk = 1.f;
  for (int k = 0; k < m; ++k) { S0 += dk; S1 += (float)k * dk; dk *= ig; }
  float GL = 12.0f * (float)m;    // l += GL * tr coefficient
  float Gd = dk;                  // seasonal decay d^m  (m==0 -> identity)
  float Gf = ab * S0;             // tr += Gf * sum(s)
  float Gc[12];
#pragma unroll
  for (int j = 0; j < 12; ++j)
    Gc[j] = fmaf(a, S0, ab * ((GL - 1.0f - (float)j) * S0 - 12.0f * S1));
  float Pl = l, Pt = tr, Ps[12];
#pragma unroll
  for (int j = 0; j < 12; ++j) Ps[j] = s[j];

  // ---- Kogge-Stone inclusive scan of affine maps --------------------------
  // compose(first = other (earlier lanes), second = current):
  //   L' = oL + L;  d' = od*d;  f' = of + f*od;  c'_j = oc_j + L*of + c_j*od
  //   ps'_j = d*ops_j + ps_j;  pt' = opt + f*sum(ops) + pt;
  //   pl' = opl + L*opt + dot(c, ops) + pl
#pragma unroll
  for (int dlt = 1; dlt < 64; dlt <<= 1) {
    float oL  = __shfl_up(GL, dlt, 64);
    float od  = __shfl_up(Gd, dlt, 64);
    float of  = __shfl_up(Gf, dlt, 64);
    float oPl = __shfl_up(Pl, dlt, 64);
    float oPt = __shfl_up(Pt, dlt, 64);
    float oc[12], oPs[12];
#pragma unroll
    for (int j = 0; j < 12; ++j) {
      oc[j]  = __shfl_up(Gc[j], dlt, 64);
      oPs[j] = __shfl_up(Ps[j], dlt, 64);
    }
    if (lane >= dlt) {
      float sum_oPs = 0.f, dot = 0.f;
#pragma unroll
      for (int j = 0; j < 12; ++j) {
        sum_oPs += oPs[j];
        dot = fmaf(Gc[j], oPs[j], dot);
      }
      float nPl = oPl + GL * oPt + dot + Pl;
      float nPt = oPt + Gf * sum_oPs + Pt;
#pragma unroll
      for (int j = 0; j < 12; ++j) {
        Ps[j] = fmaf(Gd, oPs[j], Ps[j]);
        Gc[j] = oc[j] + GL * of + Gc[j] * od;
      }
      Pl = nPl; Pt = nPt;
      Gf = of + Gf * od;
      Gd = od * Gd;
      GL = oL + GL;
    }
  }

  // ---- apply inclusive map to x0 -> state AFTER this lane's chunk ---------
  const float l0 = lvl0[n], tr00 = tr0[n];
  float s0[12];
#pragma unroll
  for (int j = 0; j < 12; ++j) s0[j] = seas0[(size_t)n * 12 + j];
  float ss = 0.f, cdot = 0.f;
#pragma unroll
  for (int j = 0; j < 12; ++j) { ss += s0[j]; cdot = fmaf(Gc[j], s0[j], cdot); }
  float yl = l0 + GL * tr00 + cdot + Pl;
  float yt = tr00 + Gf * ss + Pt;
  float ys[12];
#pragma unroll
  for (int j = 0; j < 12; ++j) ys[j] = fmaf(Gd, s0[j], Ps[j]);

  // exclusive shift: lane's true initial state = previous lane's inclusive
  l  = __shfl_up(yl, 1, 64);
  tr = __shfl_up(yt, 1, 64);
#pragma unroll
  for (int j = 0; j < 12; ++j) s[j] = __shfl_up(ys[j], 1, 64);
  if (lane == 0) {
    l = l0; tr = tr00;
#pragma unroll
    for (int j = 0; j < 12; ++j) s[j] = s0[j];
  }

  // ---- pass2: emit y (overwrites err slots in LDS) ------------------------
  {
    int t = t0;
    for (int u = 0; u < m; ++u, t += 12) {
#pragma unroll
      for (int j = 0; j < 12; ++j) {
        int ad = SKEW(t + j);
        float e = er_s[ad], o = ob_s[ad];
        float lt = l + tr;
        float cur = lt + s[j];
        er_s[ad] = fmaf(o, 0.1f, cur);
        float se = s[j] + e;
        l  = fmaf(a, se, lt);
        tr = fmaf(ab, se, tr);
        s[j] = fmaf(g, e, ig * s[j]);
      }
    }
  }
  // tail (< 12 steps, slot phase 0) continues from the last lane's state
  if (lane == 63) {
    int tt = nper * 12;
    int tail = T - tt;
#pragma unroll
    for (int j = 0; j < 11; ++j) {
      if (j < tail) {
        int ad = SKEW(tt + j);
        float e = er_s[ad], o = ob_s[ad];
        float lt = l + tr;
        float cur = lt + s[j];
        er_s[ad] = fmaf(o, 0.1f, cur);
        float se = s[j] + e;
        l  = fmaf(a, se, lt);
        tr = fmaf(ab, se, tr);
        s[j] = fmaf(g, e, ig * s[j]);
      }
    }
  }

  __syncthreads();

  // Coalesced store-out.
  float4* Y4 = reinterpret_cast<float4*>(out + (size_t)n * T);
#pragma unroll 4
  for (int i = lane; i < nf4; i += 64) {
    int j = i << 2;
    float4 v = make_float4(er_s[SKEW(j + 0)], er_s[SKEW(j + 1)],
                           er_s[SKEW(j + 2)], er_s[SKEW(j + 3)]);
    Y4[i] = v;
  }
}

// ---------------------------------------------------------------------------
// Generic fallback (any P/T): one thread per series, seasonal state in LDS.
// ---------------------------------------------------------------------------
__global__ void ets_gen(
    const float* __restrict__ alpha_, const float* __restrict__ beta_,
    const float* __restrict__ gamma_, const float* __restrict__ lvl0,
    const float* __restrict__ tr0, const float* __restrict__ seas0,
    const float* __restrict__ obs, const float* __restrict__ err,
    float* __restrict__ out, int N, int T, int P)
{
  extern __shared__ float smem[];
  int n = blockIdx.x * blockDim.x + threadIdx.x;
  if (n >= N) return;
  float* s = smem + (size_t)threadIdx.x * P;
  for (int j = 0; j < P; ++j) s[j] = seas0[(size_t)n * P + j];

  float a = alpha_[n], b = beta_[n], g = gamma_[n];
  float ia = 1.0f - a, ib = 1.0f - b, ig = 1.0f - g;
  float level = lvl0[n], trend = tr0[n];

  const float* on = obs + (size_t)n * T;
  const float* er = err + (size_t)n * T;
  float*       yo = out + (size_t)n * T;

  int idx = 0;
  for (int t = 0; t < T; ++t) {
    float onj = on[t], ej = er[t];
    float sj  = s[idx];
    float cur = level + trend + sj;
    yo[t] = fmaf(onj, 0.1f, cur);
    float lt  = level + trend;
    float nl  = fmaf(a, cur + ej, ia * lt);
    float nt  = fmaf(b, nl - level, ib * trend);
    s[idx]    = fmaf(g, ej, ig * sj);
    level = nl; trend = nt;
    if (++idx == P) idx = 0;
  }
}

extern "C" void kernel_launch(void* const* d_in, const int* in_sizes, int n_in,
                              void* d_out, int out_size, void* d_ws, size_t ws_size,
                              hipStream_t stream) {
  (void)n_in; (void)out_size; (void)d_ws; (void)ws_size;
  const float* alpha = (const float*)d_in[0];
  const float* beta  = (const float*)d_in[1];
  const float* gamma = (const float*)d_in[2];
  const float* lvl0  = (const float*)d_in[3];
  const float* tr0   = (const float*)d_in[4];
  const float* seas0 = (const float*)d_in[5];
  const float* obs   = (const float*)d_in[6];
  const float* err   = (const float*)d_in[7];
  float* y = (float*)d_out;

  int N = in_sizes[0];
  int P = in_sizes[5] / N;
  int T = in_sizes[6] / N;

  if (P == 12 && (T % 4) == 0 && T >= 12 && T <= 4096) {
    ets_wave<<<dim3(N), dim3(64), 0, stream>>>(
        alpha, beta, gamma, lvl0, tr0, seas0, obs, err, y, T);
  } else {
    int bs = 64;
    size_t sh = (size_t)bs * (size_t)P * sizeof(float);
    ets_gen<<<dim3((N + bs - 1) / bs), dim3(bs), sh, stream>>>(
        alpha, beta, gamma, lvl0, tr0, seas0, obs, err, y, N, T, P);
  }
}

// Round 6
// 47.350 us; speedup vs baseline: 3.5228x; 1.4089x over previous
//
#include <hip/hip_runtime.h>

#define DEV static __device__ __forceinline__

// Skewed LDS addressing: physical = j + j/32. Breaks the 72-float chunk
// stride (multiple of 32 banks) into ~2-way conflicts. Max phys for T=4096:
// 4095 + 127 = 4222 < 4224.
#define SKEW(j) ((j) + ((j) >> 5))

// ---------------------------------------------------------------------------
// Wave-per-series kernel (P == 12, T % 4 == 0, 12 <= T <= 4096).
//
// One 64-lane wave owns one series. Only the err row is staged to LDS
// (16.9 KB/block -> 9 blocks/CU vs 4 with obs staged too). obs is consumed
// coalesced at store-out time as y = cur + 0.1*obs. Lane l owns m(l) whole
// seasonal periods. The ETS state x = (level, trend, s[0..11]) evolves
// affinely; over whole periods the homogeneous map lives in the 15-param
// family  l -> l + L*tr + sum_j c_j s_j ; tr -> tr + f*sum_j s_j ; s_j -> d*s_j
// which is closed under composition. Per-lane map: analytic geometric sums of
// d = 1-gamma; particular part: pass1 recurrence from zero state. A 6-round
// Kogge-Stone shuffle scan composes the 64 per-lane affine maps; lane l then
// gets its true initial state and pass2 writes `cur` back into the consumed
// err LDS slots. Single dispatch, no global workspace.
// ---------------------------------------------------------------------------
__global__ __launch_bounds__(64) void ets_wave(
    const float* __restrict__ alpha_, const float* __restrict__ beta_,
    const float* __restrict__ gamma_, const float* __restrict__ lvl0,
    const float* __restrict__ tr0, const float* __restrict__ seas0,
    const float* __restrict__ obs, const float* __restrict__ err,
    float* __restrict__ out, int T)
{
  __shared__ float er_s[4224];  // err, recycled for `cur` in pass2

  const int n = blockIdx.x;
  const int lane = threadIdx.x;

  const float4* ER4 = reinterpret_cast<const float4*>(err + (size_t)n * T);
  const float4* OB4 = reinterpret_cast<const float4*>(obs + (size_t)n * T);
  const int nf4 = T >> 2;

  // Coalesced stage-in: 1 KB per wave load instruction.
#pragma unroll 4
  for (int i = lane; i < nf4; i += 64) {
    float4 e = ER4[i];
    int j = i << 2;
    er_s[SKEW(j + 0)] = e.x; er_s[SKEW(j + 1)] = e.y;
    er_s[SKEW(j + 2)] = e.z; er_s[SKEW(j + 3)] = e.w;
  }

  const float a = alpha_[n], b = beta_[n], g = gamma_[n];
  const float ab = a * b, ig = 1.0f - g;

  const int nper = T / 12;
  const int base = nper >> 6, rem = nper & 63;
  const int m  = base + (lane < rem ? 1 : 0);           // periods this lane owns
  const int p0 = lane * base + min(lane, rem);          // first period
  const int t0 = p0 * 12;

  __syncthreads();

  // ---- pass1: particular solution from zero state -------------------------
  float l = 0.f, tr = 0.f, s[12];
#pragma unroll
  for (int j = 0; j < 12; ++j) s[j] = 0.f;
  {
    int t = t0;
    for (int u = 0; u < m; ++u, t += 12) {
#pragma unroll
      for (int j = 0; j < 12; ++j) {
        float e = er_s[SKEW(t + j)];
        float se = s[j] + e;
        float lt = l + tr;
        l  = fmaf(a, se, lt);
        tr = fmaf(ab, se, tr);
        s[j] = fmaf(g, e, ig * s[j]);
      }
    }
  }

  // ---- analytic homogeneous map for this lane's m periods -----------------
  float S0 = 0.f, S1 = 0.f, dk = 1.f;
  for (int k = 0; k < m; ++k) { S0 += dk; S1 += (float)k * dk; dk *= ig; }
  float GL = 12.0f * (float)m;    // l += GL * tr coefficient
  float Gd = dk;                  // seasonal decay d^m  (m==0 -> identity)
  float Gf = ab * S0;             // tr += Gf * sum(s)
  float Gc[12];
#pragma unroll
  for (int j = 0; j < 12; ++j)
    Gc[j] = fmaf(a, S0, ab * ((GL - 1.0f - (float)j) * S0 - 12.0f * S1));
  float Pl = l, Pt = tr, Ps[12];
#pragma unroll
  for (int j = 0; j < 12; ++j) Ps[j] = s[j];

  // ---- Kogge-Stone inclusive scan of affine maps --------------------------
  // compose(first = other (earlier lanes), second = current):
  //   L' = oL + L;  d' = od*d;  f' = of + f*od;  c'_j = oc_j + L*of + c_j*od
  //   ps'_j = d*ops_j + ps_j;  pt' = opt + f*sum(ops) + pt;
  //   pl' = opl + L*opt + dot(c, ops) + pl
#pragma unroll
  for (int dlt = 1; dlt < 64; dlt <<= 1) {
    float oL  = __shfl_up(GL, dlt, 64);
    float od  = __shfl_up(Gd, dlt, 64);
    float of  = __shfl_up(Gf, dlt, 64);
    float oPl = __shfl_up(Pl, dlt, 64);
    float oPt = __shfl_up(Pt, dlt, 64);
    float oc[12], oPs[12];
#pragma unroll
    for (int j = 0; j < 12; ++j) {
      oc[j]  = __shfl_up(Gc[j], dlt, 64);
      oPs[j] = __shfl_up(Ps[j], dlt, 64);
    }
    if (lane >= dlt) {
      float sum_oPs = 0.f, dot = 0.f;
#pragma unroll
      for (int j = 0; j < 12; ++j) {
        sum_oPs += oPs[j];
        dot = fmaf(Gc[j], oPs[j], dot);
      }
      float nPl = oPl + GL * oPt + dot + Pl;
      float nPt = oPt + Gf * sum_oPs + Pt;
#pragma unroll
      for (int j = 0; j < 12; ++j) {
        Ps[j] = fmaf(Gd, oPs[j], Ps[j]);
        Gc[j] = oc[j] + GL * of + Gc[j] * od;
      }
      Pl = nPl; Pt = nPt;
      Gf = of + Gf * od;
      Gd = od * Gd;
      GL = oL + GL;
    }
  }

  // ---- apply inclusive map to x0 -> state AFTER this lane's chunk ---------
  const float l0 = lvl0[n], tr00 = tr0[n];
  float s0[12];
#pragma unroll
  for (int j = 0; j < 12; ++j) s0[j] = seas0[(size_t)n * 12 + j];
  float ss = 0.f, cdot = 0.f;
#pragma unroll
  for (int j = 0; j < 12; ++j) { ss += s0[j]; cdot = fmaf(Gc[j], s0[j], cdot); }
  float yl = l0 + GL * tr00 + cdot + Pl;
  float yt = tr00 + Gf * ss + Pt;
  float ys[12];
#pragma unroll
  for (int j = 0; j < 12; ++j) ys[j] = fmaf(Gd, s0[j], Ps[j]);

  // exclusive shift: lane's true initial state = previous lane's inclusive
  l  = __shfl_up(yl, 1, 64);
  tr = __shfl_up(yt, 1, 64);
#pragma unroll
  for (int j = 0; j < 12; ++j) s[j] = __shfl_up(ys[j], 1, 64);
  if (lane == 0) {
    l = l0; tr = tr00;
#pragma unroll
    for (int j = 0; j < 12; ++j) s[j] = s0[j];
  }

  // ---- pass2: write `cur` into the consumed err slots ---------------------
  {
    int t = t0;
    for (int u = 0; u < m; ++u, t += 12) {
#pragma unroll
      for (int j = 0; j < 12; ++j) {
        int ad = SKEW(t + j);
        float e = er_s[ad];
        float lt = l + tr;
        float cur = lt + s[j];
        er_s[ad] = cur;                 // y minus the 0.1*obs term
        float se = s[j] + e;
        l  = fmaf(a, se, lt);
        tr = fmaf(ab, se, tr);
        s[j] = fmaf(g, e, ig * s[j]);
      }
    }
  }
  // tail (< 12 steps, slot phase 0) continues from the last lane's state
  if (lane == 63) {
    int tt = nper * 12;
    int tail = T - tt;
#pragma unroll
    for (int j = 0; j < 11; ++j) {
      if (j < tail) {
        int ad = SKEW(tt + j);
        float e = er_s[ad];
        float lt = l + tr;
        float cur = lt + s[j];
        er_s[ad] = cur;
        float se = s[j] + e;
        l  = fmaf(a, se, lt);
        tr = fmaf(ab, se, tr);
        s[j] = fmaf(g, e, ig * s[j]);
      }
    }
  }

  __syncthreads();

  // Coalesced store-out, fusing y = cur + 0.1*obs with a coalesced obs read.
  float4* Y4 = reinterpret_cast<float4*>(out + (size_t)n * T);
#pragma unroll 4
  for (int i = lane; i < nf4; i += 64) {
    float4 o = OB4[i];
    int j = i << 2;
    float4 v = make_float4(fmaf(o.x, 0.1f, er_s[SKEW(j + 0)]),
                           fmaf(o.y, 0.1f, er_s[SKEW(j + 1)]),
                           fmaf(o.z, 0.1f, er_s[SKEW(j + 2)]),
                           fmaf(o.w, 0.1f, er_s[SKEW(j + 3)]));
    Y4[i] = v;
  }
}

// ---------------------------------------------------------------------------
// Generic fallback (any P/T): one thread per series, seasonal state in LDS.
// ---------------------------------------------------------------------------
__global__ void ets_gen(
    const float* __restrict__ alpha_, const float* __restrict__ beta_,
    const float* __restrict__ gamma_, const float* __restrict__ lvl0,
    const float* __restrict__ tr0, const float* __restrict__ seas0,
    const float* __restrict__ obs, const float* __restrict__ err,
    float* __restrict__ out, int N, int T, int P)
{
  extern __shared__ float smem[];
  int n = blockIdx.x * blockDim.x + threadIdx.x;
  if (n >= N) return;
  float* s = smem + (size_t)threadIdx.x * P;
  for (int j = 0; j < P; ++j) s[j] = seas0[(size_t)n * P + j];

  float a = alpha_[n], b = beta_[n], g = gamma_[n];
  float ia = 1.0f - a, ib = 1.0f - b, ig = 1.0f - g;
  float level = lvl0[n], trend = tr0[n];

  const float* on = obs + (size_t)n * T;
  const float* er = err + (size_t)n * T;
  float*       yo = out + (size_t)n * T;

  int idx = 0;
  for (int t = 0; t < T; ++t) {
    float onj = on[t], ej = er[t];
    float sj  = s[idx];
    float cur = level + trend + sj;
    yo[t] = fmaf(onj, 0.1f, cur);
    float lt  = level + trend;
    float nl  = fmaf(a, cur + ej, ia * lt);
    float nt  = fmaf(b, nl - level, ib * trend);
    s[idx]    = fmaf(g, ej, ig * sj);
    level = nl; trend = nt;
    if (++idx == P) idx = 0;
  }
}

extern "C" void kernel_launch(void* const* d_in, const int* in_sizes, int n_in,
                              void* d_out, int out_size, void* d_ws, size_t ws_size,
                              hipStream_t stream) {
  (void)n_in; (void)out_size; (void)d_ws; (void)ws_size;
  const float* alpha = (const float*)d_in[0];
  const float* beta  = (const float*)d_in[1];
  const float* gamma = (const float*)d_in[2];
  const float* lvl0  = (const float*)d_in[3];
  const float* tr0   = (const float*)d_in[4];
  const float* seas0 = (const float*)d_in[5];
  const float* obs   = (const float*)d_in[6];
  const float* err   = (const float*)d_in[7];
  float* y = (float*)d_out;

  int N = in_sizes[0];
  int P = in_sizes[5] / N;
  int T = in_sizes[6] / N;

  if (P == 12 && (T % 4) == 0 && T >= 12 && T <= 4096) {
    ets_wave<<<dim3(N), dim3(64), 0, stream>>>(
        alpha, beta, gamma, lvl0, tr0, seas0, obs, err, y, T);
  } else {
    int bs = 64;
    size_t sh = (size_t)bs * (size_t)P * sizeof(float);
    ets_gen<<<dim3((N + bs - 1) / bs), dim3(bs), sh, stream>>>(
        alpha, beta, gamma, lvl0, tr0, seas0, obs, err, y, N, T, P);
  }
}